// Round 2
// 47.537 us; speedup vs baseline: 1.1870x; 1.1870x over previous
//
#include <hip/hip_runtime.h>

// Problem constants (fixed by setup_inputs).
constexpr int kB = 4;
constexpr int kN = 8192;   // points
constexpr int kP = 2048;   // queries
constexpr int kS = 32;     // samples per query
constexpr int kC = 64;     // feature channels
constexpr int kCO = 67;    // output channels (3 xyz + 64 features)
constexpr float kR2 = 0.0144f;  // f32(0.12*0.12)

// Exact numpy f32 op order; __f*_rn blocks FMA contraction. DO NOT REORDER —
// this sequence passes with absmax 0.0 (bit-exact vs np reference, r2/3/6).
__device__ __forceinline__ float sq3(float x, float y, float z) {
  return __fadd_rn(__fadd_rn(__fmul_rn(x, x), __fmul_rn(y, y)),
                   __fmul_rn(z, z));
}
__device__ __forceinline__ float dot3(float ax, float ay, float az, float bx,
                                      float by, float bz) {
  return __fadd_rn(__fadd_rn(__fmul_rn(ax, bx), __fmul_rn(ay, by)),
                   __fmul_rn(az, bz));
}

// ---------------------------------------------------------------------------
// Kernel 1: ball query — ROUND-0 PROVEN, VERBATIM (bit-exact g_idx producer).
// Grid: kB*kP/8 = 1024 blocks x 256 threads (4 waves), 2 queries per wave.
// ---------------------------------------------------------------------------
__global__ __launch_bounds__(256) void bq_k(const float* __restrict__ xyz,
                                            const float* __restrict__ new_xyz,
                                            int* __restrict__ g_idx) {
  __shared__ unsigned short sidx[4][2][32];  // [wave][query][slot]
  __shared__ int scnt[4][2];

  const int tid = threadIdx.x;
  const int wv = tid >> 6;
  const int lane = tid & 63;
  const int w = blockIdx.x * 4 + wv;  // global wave id, < 4096
  const int q0 = w * 2;               // first of this wave's 2 queries
  const int b = q0 >> 11;             // kP = 2048
  const int p = q0 & (kP - 1);

  const float* xb = xyz + (size_t)b * kN * 3;
  const float* qb = new_xyz + ((size_t)b * kP + p) * 3;

  const float qx0 = qb[0], qy0 = qb[1], qz0 = qb[2];
  const float qx1 = qb[3], qy1 = qb[4], qz1 = qb[5];
  const float qq0 = sq3(qx0, qy0, qz0);
  const float qq1 = sq3(qx1, qy1, qz1);

  const unsigned long long lmask = (1ull << lane) - 1ull;
  int cnt0 = 0, cnt1 = 0;

#define PROC(j)                                                             \
  {                                                                         \
    float d2 = __fsub_rn(__fadd_rn(qq##j, xx),                              \
                         __fmul_rn(2.0f, dot3(qx##j, qy##j, qz##j, px, py,  \
                                              pz)));                        \
    unsigned long long m = __ballot(d2 < kR2);                              \
    if (m) {                                                                \
      int pos = cnt##j + __popcll(m & lmask);                               \
      if ((d2 < kR2) && pos < kS)                                           \
        sidx[wv][j][pos] = (unsigned short)ncur;                            \
      cnt##j += __popcll(m);                                                \
    }                                                                       \
  }

  // Group-of-4-windows software pipeline. All indices compile-time constant
  // under full unroll -> arrays stay in registers.
  float cx[4], cy[4], cz[4];
#pragma unroll
  for (int k = 0; k < 4; ++k) {
    int n = k * 64 + lane;
    cx[k] = xb[3 * n + 0];
    cy[k] = xb[3 * n + 1];
    cz[k] = xb[3 * n + 2];
  }

  int gbase = 0;
  for (int g0 = 256;; g0 += 256) {
    const bool more = (g0 < kN);
    const int g1 = more ? g0 : 0;  // clamp: loads always valid, never consumed
                                   // when !more (we break before the copy)
    float nx[4], ny[4], nz[4];
#pragma unroll
    for (int k = 0; k < 4; ++k) {
      int n = g1 + k * 64 + lane;
      nx[k] = xb[3 * n + 0];
      ny[k] = xb[3 * n + 1];
      nz[k] = xb[3 * n + 2];
    }
#pragma unroll
    for (int k = 0; k < 4; ++k) {
      const float px = cx[k], py = cy[k], pz = cz[k];
      const float xx = sq3(px, py, pz);
      const int ncur = gbase + k * 64 + lane;
      PROC(0)
      PROC(1)
    }
    if (!more || (cnt0 >= kS && cnt1 >= kS)) break;
#pragma unroll
    for (int k = 0; k < 4; ++k) {
      cx[k] = nx[k];
      cy[k] = ny[k];
      cz[k] = nz[k];
    }
    gbase = g0;
  }
#undef PROC

  if (lane == 0) {
    scnt[wv][0] = cnt0;
    scnt[wv][1] = cnt1;
  }
  __syncthreads();

  // write out 2 queries x 32 slots = 64 ints per wave (one int per lane)
  const int j = lane >> 5, s = lane & 31;
  int c = scnt[wv][j];
  int first = (c > 0) ? (int)sidx[wv][j][0] : 0;
  int val = (s < c) ? (int)sidx[wv][j][s] : first;
  g_idx[((size_t)(b * kP + p + j)) * kS + s] = val;
}

// ---------------------------------------------------------------------------
// Kernel 2: gather, vectorized 4x (the ONLY change vs round-0). Same block
// decomposition and LDS staging as the proven gather_k; inner loop now does
// int4 idx load -> 4 LDS gathers -> one float4 store per lane (16 iterations
// instead of 64). 4 consecutive elements always belong to the same query
// (4 | kS), so one nxz value covers the whole float4; subtraction order
// (__fsub_rn) unchanged. Grid: kB*kCO*2 = 536 blocks x 512 thr.
// ---------------------------------------------------------------------------
__global__ __launch_bounds__(512) void gather_k2(
    const float* __restrict__ xyz, const float* __restrict__ new_xyz,
    const float* __restrict__ feat, const int* __restrict__ g_idx,
    float* __restrict__ out) {
  __shared__ float row[kN];      // 32 KB
  __shared__ float nxz[kP / 2];  // 4 KB (query-center column, c<3 only)
  const int tid = threadIdx.x;
  const int bi = blockIdx.x;
  const int b = bi / (kCO * 2);
  const int r = bi % (kCO * 2);
  const int c = r >> 1;
  const int ph = r & 1;

  if (c < 3) {
    for (int i = tid; i < kN; i += 512)
      row[i] = xyz[((size_t)b * kN + i) * 3 + c];
    for (int i = tid; i < kP / 2; i += 512)
      nxz[i] = new_xyz[((size_t)b * kP + ph * (kP / 2) + i) * 3 + c];
  } else {
    const float4* src = (const float4*)(feat + ((size_t)b * kC + (c - 3)) * kN);
    float4* dst = (float4*)row;
    for (int i = tid; i < kN / 4; i += 512) dst[i] = src[i];
  }
  __syncthreads();

  const size_t eg_base = (((size_t)b * kP + ph * (kP / 2)) * kS) >> 2;
  const int4* idx4 = (const int4*)g_idx + eg_base;
  float4* out4 =
      (float4*)out + ((((size_t)b * kCO + c) * kP + ph * (kP / 2)) * kS >> 2);
  const bool isxyz = (c < 3);
#pragma unroll 4
  for (int it = 0; it < (kP / 2) * kS / 4 / 512; ++it) {  // 16 iterations
    const int e4 = it * 512 + tid;                        // element = 4*e4
    const int4 n = idx4[e4];
    float4 v = make_float4(row[n.x], row[n.y], row[n.z], row[n.w]);
    if (isxyz) {
      const float sub = nxz[e4 >> 3];  // query = (4*e4)>>5 = e4>>3
      v.x = __fsub_rn(v.x, sub);
      v.y = __fsub_rn(v.y, sub);
      v.z = __fsub_rn(v.z, sub);
      v.w = __fsub_rn(v.w, sub);
    }
    out4[e4] = v;
  }
}

// ---------------------------------------------------------------------------
// Fallback: round-2 fused kernel (known-passing), used only if ws too small.
// ---------------------------------------------------------------------------
__global__ __launch_bounds__(512) void fused_qg(
    const float* __restrict__ xyz, const float* __restrict__ new_xyz,
    const float* __restrict__ feat, float* __restrict__ out) {
  __shared__ __align__(16) char ls[32768 + 512 + 4096];
  unsigned short (*sidx)[64][32] = (unsigned short (*)[64][32])ls;
  float* row = (float*)ls;
  unsigned char (*scnt)[64] = (unsigned char (*)[64])(ls + 32768);
  unsigned short (*midx)[32] = (unsigned short (*)[32])(ls + 32768 + 512);

  const int tid = threadIdx.x;
  const int wv = tid >> 6;
  const int lane = tid & 63;
  const int b = blockIdx.x >> 5;
  const int p0 = (blockIdx.x & 31) << 6;

  {
    const float* q = &new_xyz[(b * kP + p0 + lane) * 3];
    const float qx = q[0], qy = q[1], qz = q[2];
    const float qq = sq3(qx, qy, qz);
    const float* xb = xyz + ((size_t)b * kN + wv * 1024) * 3;
    int cnt = 0;
    for (int i = 0; i < 1024; ++i) {
      float px = xb[i * 3 + 0], py = xb[i * 3 + 1], pz = xb[i * 3 + 2];
      float xx = sq3(px, py, pz);
      float d2 = __fsub_rn(__fadd_rn(qq, xx),
                           __fmul_rn(2.0f, dot3(qx, qy, qz, px, py, pz)));
      if (d2 < kR2 && cnt < kS) {
        sidx[wv][lane][cnt] = (unsigned short)(wv * 1024 + i);
        ++cnt;
      }
    }
    scnt[wv][lane] = (unsigned char)cnt;
  }
  __syncthreads();

  if (tid < 64) {
    int filled = 0, first = 0;
    bool has = false;
    for (int sg = 0; sg < 8 && filled < kS; ++sg) {
      int c = scnt[sg][tid];
      for (int k = 0; k < c && filled < kS; ++k) {
        int n = sidx[sg][tid][k];
        if (!has) { first = n; has = true; }
        midx[tid][filled++] = (unsigned short)n;
      }
    }
    for (; filled < kS; ++filled) midx[tid][filled] = (unsigned short)first;
  }

  for (int c = 0; c < kCO; ++c) {
    __syncthreads();
    if (c < 3) {
      for (int i = tid; i < kN; i += 512)
        row[i] = xyz[((size_t)b * kN + i) * 3 + c];
    } else {
      const float4* src =
          (const float4*)(feat + ((size_t)b * kC + (c - 3)) * kN);
      float4* dst = (float4*)row;
      for (int i = tid; i < kN / 4; i += 512) dst[i] = src[i];
    }
    __syncthreads();
    const int outbase = ((b * kCO + c) * kP + p0) * kS;
    for (int e = tid; e < 64 * kS; e += 512) {
      int n = midx[e >> 5][e & 31];
      float v = row[n];
      if (c < 3) v = __fsub_rn(v, new_xyz[(b * kP + p0 + (e >> 5)) * 3 + c]);
      out[outbase + e] = v;
    }
  }
}

// ---------------------------------------------------------------------------
extern "C" void kernel_launch(void* const* d_in, const int* in_sizes, int n_in,
                              void* d_out, int out_size, void* d_ws,
                              size_t ws_size, hipStream_t stream) {
  const float* xyz = (const float*)d_in[0];      // [B,N,3]
  const float* new_xyz = (const float*)d_in[1];  // [B,P,3]
  const float* feat = (const float*)d_in[2];     // [B,C,N]
  float* out = (float*)d_out;                    // [B,67,P,S]

  const size_t idx_bytes = (size_t)kB * kP * kS * sizeof(int);  // 1 MB
  if (ws_size >= idx_bytes) {
    int* g_idx = (int*)d_ws;
    bq_k<<<dim3(kB * kP / 8), dim3(256), 0, stream>>>(xyz, new_xyz, g_idx);
    gather_k2<<<dim3(kB * kCO * 2), dim3(512), 0, stream>>>(xyz, new_xyz, feat,
                                                            g_idx, out);
  } else {
    fused_qg<<<dim3(kB * (kP / 64)), dim3(512), 0, stream>>>(xyz, new_xyz,
                                                             feat, out);
  }
}